// Round 1
// baseline (1188.253 us; speedup 1.0000x reference)
//
#include <hip/hip_runtime.h>

#define NS 2048      // series = 256*8
#define T 4096
#define F 9
#define CH 64        // p3 outputs per chunk
#define NCHUNK 9     // ceil(513/64)

// LDS layout (floats)
#define SM_W1 0        // 432  : w1 transposed [fk][c]
#define SM_B1 432      // 16
#define SM_W2 448      // 1536 : w2 transposed [ik][o]
#define SM_B2 1984     // 32
#define SM_W3 2016     // 1536 : w3 transposed [ik][o]
#define SM_B3 3552     // 16
#define SM_P1 3568     // 4192 = 262*16
#define SM_R2 7760     // 4734 = max(526*9 sx, 130*32 p2)  (union: sx dead before p2 written)
#define SM_ACC 12494   // 16
#define SM_TOT 12510   // 50040 bytes

__global__ __launch_bounds__(256) void fused_cnn(
    const float* __restrict__ x,
    const float* __restrict__ w1, const float* __restrict__ b1,
    const float* __restrict__ w2, const float* __restrict__ b2,
    const float* __restrict__ w3, const float* __restrict__ b3,
    float* __restrict__ feat)
{
    __shared__ float sm[SM_TOT];
    const int tid = threadIdx.x;
    const int chunk = blockIdx.x;
    const int n = blockIdx.y;
    const int r0 = chunk * CH;
    const int nr = min(CH, 513 - r0);   // 64 or 1 (last chunk)
    const int nw = 2*nr + 2;            // p2 rows needed
    const int nu = 4*nr + 6;            // p1 rows needed
    const int nx = 8*nr + 14;           // x rows needed

    // ---- weights -> LDS, transposed so per-lane preload is conflict-free ----
    for (int i = tid; i < 432; i += 256) {          // w1[c][f][k] -> [fk][c]
        int c = i / 27, fk = i - c*27;
        sm[SM_W1 + fk*16 + c] = w1[i];
    }
    for (int i = tid; i < 1536; i += 256) {         // w2[o][ik] -> [ik][o]
        int o = i / 48, ik = i - o*48;
        sm[SM_W2 + ik*32 + o] = w2[i];
    }
    for (int i = tid; i < 1536; i += 256) {         // w3[o][ik] -> [ik][o]
        int o = i / 96, ik = i - o*96;
        sm[SM_W3 + ik*16 + o] = w3[i];
    }
    if (tid < 16) sm[SM_B1 + tid] = b1[tid];
    if (tid < 32) sm[SM_B2 + tid] = b2[tid];
    if (tid < 16) sm[SM_B3 + tid] = b3[tid];
    if (tid < 16) sm[SM_ACC + tid] = 0.f;

    // ---- stage A: x chunk -> LDS (coalesced flat copy, zero outside [0,T)) ----
    {
        float* sx = sm + SM_R2;
        const float* xs = x + (size_t)n * (T*F);
        const int base = (8*r0 - 14) * F;
        const int tot = nx * F;
        for (int i = tid; i < tot; i += 256) {
            int gi = base + i;
            sx[i] = (gi >= 0 && gi < T*F) ? xs[gi] : 0.f;
        }
    }
    __syncthreads();

    // ---- stage B: conv1 (9ch,k=3) + relu + pool2 -> p1[nu][16] ----
    {
        const int c = tid & 15;
        float wr[27];
        #pragma unroll
        for (int j = 0; j < 27; ++j) wr[j] = sm[SM_W1 + j*16 + c];
        const float bc = sm[SM_B1 + c];
        const float* sx = sm + SM_R2;
        float* p1 = sm + SM_P1;
        for (int ul = tid >> 4; ul < nu; ul += 16) {
            const int u = r0*4 - 6 + ul;
            float res = 0.f;
            if (u >= 0 && u < 2049) {
                // c1[2u] window starts at local x-row 2ul (tau = 2u-2), c1[2u+1] at 2ul+1
                const float* xw = sx + (2*ul)*F;
                float a0 = bc, a1 = bc;
                #pragma unroll
                for (int k = 0; k < 3; ++k) {
                    #pragma unroll
                    for (int f = 0; f < 9; ++f) {
                        float wv = wr[f*3 + k];
                        a0 = fmaf(xw[k*F + f],     wv, a0);
                        a1 = fmaf(xw[(k+1)*F + f], wv, a1);
                    }
                }
                res = fmaxf(fmaxf(a0, a1), 0.f);
            }
            p1[ul*16 + c] = res;  // zero for out-of-range u (conv padding for stage 2)
        }
    }
    __syncthreads();

    // ---- stage C: conv2 (16ch,k=3) + relu + pool2 -> p2[nw][32] (overwrites sx) ----
    {
        const int o = tid & 31;
        float wr[48];
        #pragma unroll
        for (int j = 0; j < 48; ++j) wr[j] = sm[SM_W2 + j*32 + o];
        const float bo = sm[SM_B2 + o];
        const float* p1 = sm + SM_P1;
        float* p2 = sm + SM_R2;
        for (int wl = tid >> 5; wl < nw; wl += 8) {
            const int w = r0*2 - 2 + wl;
            float res = 0.f;
            if (w >= 0 && w < 1025) {
                const float* pw = p1 + (2*wl)*16;   // rows 2wl..2wl+3
                float a0 = bo, a1 = bo;
                #pragma unroll
                for (int k = 0; k < 3; ++k) {
                    #pragma unroll
                    for (int i = 0; i < 16; ++i) {
                        float wv = wr[i*3 + k];
                        a0 = fmaf(pw[k*16 + i],     wv, a0);
                        a1 = fmaf(pw[(k+1)*16 + i], wv, a1);
                    }
                }
                res = fmaxf(fmaxf(a0, a1), 0.f);
            }
            p2[wl*32 + o] = res;
        }
    }
    __syncthreads();

    // ---- stage D: conv3 (32ch,k=3) + relu + pool2 -> running sum over r ----
    {
        const int o = tid & 15;
        float wr[96];
        #pragma unroll
        for (int j = 0; j < 96; ++j) wr[j] = sm[SM_W3 + j*16 + o];
        const float bo = sm[SM_B3 + o];
        const float* p2 = sm + SM_R2;
        float lsum = 0.f;
        for (int rl = tid >> 4; rl < nr; rl += 16) {
            const float* pw = p2 + (2*rl)*32;   // rows 2rl..2rl+3
            float a0 = bo, a1 = bo;
            #pragma unroll
            for (int k = 0; k < 3; ++k) {
                #pragma unroll
                for (int i = 0; i < 32; ++i) {
                    float wv = wr[i*3 + k];
                    a0 = fmaf(pw[k*32 + i],     wv, a0);
                    a1 = fmaf(pw[(k+1)*32 + i], wv, a1);
                }
            }
            lsum += fmaxf(fmaxf(a0, a1), 0.f);
        }
        atomicAdd(&sm[SM_ACC + o], lsum);
        __syncthreads();
        if (tid < 16) atomicAdd(&feat[n*16 + tid], sm[SM_ACC + tid]);
    }
}

// feat [2048,16] viewed as [256,128]; out[b][q] = max(feat[b,3q..3q+2]) / 513
__global__ void finalize_kernel(const float* __restrict__ feat, float* __restrict__ out) {
    int i = blockIdx.x * blockDim.x + threadIdx.x;
    if (i < 256*42) {
        int b = i / 42;
        int q = i - b*42;
        const float* f = feat + b*128 + q*3;
        out[i] = fmaxf(fmaxf(f[0], f[1]), f[2]) * (1.0f/513.0f);
    }
}

extern "C" void kernel_launch(void* const* d_in, const int* in_sizes, int n_in,
                              void* d_out, int out_size, void* d_ws, size_t ws_size,
                              hipStream_t stream) {
    const float* x  = (const float*)d_in[0];
    const float* w1 = (const float*)d_in[1];
    const float* b1 = (const float*)d_in[2];
    const float* w2 = (const float*)d_in[3];
    const float* b2 = (const float*)d_in[4];
    const float* w3 = (const float*)d_in[5];
    const float* b3 = (const float*)d_in[6];
    float* feat = (float*)d_ws;                       // 2048*16 floats = 128 KB
    hipMemsetAsync(feat, 0, NS*16*sizeof(float), stream);
    dim3 grid(NCHUNK, NS);
    fused_cnn<<<grid, 256, 0, stream>>>(x, w1, b1, w2, b2, w3, b3, feat);
    finalize_kernel<<<(256*42 + 255)/256, 256, 0, stream>>>(feat, (float*)d_out);
}

// Round 2
// 951.759 us; speedup vs baseline: 1.2485x; 1.2485x over previous
//
#include <hip/hip_runtime.h>

#define NS 2048      // series = 256*8
#define T 4096
#define F 9
#define CH 62        // pooled-final rows per chunk -> nw=126 (2 clean strips)
#define NCHUNK 9     // 8*62=496, last chunk nr=17

// LDS: channel-major, time-contiguous, even strides
#define LXP 514      // x:  [9][514]   rows t_local in [0,510)
#define LUP 258      // p1: [16][258]  rows j in [0,254)
#define LWP 130      // p2: [32][130]  rows m in [0,126)
#define SM_X  0                  // 9*514  = 4626 floats
#define SM_P2 0                  // 32*130 = 4160 floats (overlaps X; X dead by then)
#define SM_P1 4640               // 16*258 = 4128 floats
#define SM_TOT (4640 + 16*258)   // 8768 floats = 35072 B -> 4 blocks/CU

__global__ __launch_bounds__(256, 4) void fused_cnn(
    const float* __restrict__ x,
    const float* __restrict__ w1, const float* __restrict__ b1,
    const float* __restrict__ w2, const float* __restrict__ b2,
    const float* __restrict__ w3, const float* __restrict__ b3,
    float* __restrict__ feat)
{
    __shared__ float sm[SM_TOT];
    const int tid  = threadIdx.x;
    const int lane = tid & 63;
    const int wid  = tid >> 6;          // wave id 0..3
    const int chunk = blockIdx.x;
    const int n     = blockIdx.y;
    const int r0 = chunk * CH;
    const int nr = min(CH, 513 - r0);   // 62, or 17 on last chunk
    const int nw = 2*nr + 2;            // p2 rows
    const int nu = 4*nr + 6;            // p1 rows
    const int nx = 8*nr + 14;           // x rows

    // ---- stage A: x window -> LDS transposed [f][t_local], zero-padded ----
    {
        const float* xs = x + (size_t)n * (T*F);
        const int gbase = (8*r0 - 14) * F;   // = t0*9
        const int tot = nx * F;
        for (int i = tid; i < tot; i += 256) {
            int tl = i / 9;
            int f  = i - tl*9;
            int gi = gbase + i;
            float v = (gi >= 0 && gi < T*F) ? xs[gi] : 0.f;
            sm[SM_X + f*LXP + tl] = v;
        }
    }
    __syncthreads();

    // ---- stage B: conv1(9->16,k3,p2)+relu+pool2 -> p1[c][j] ----
    {
        const int SB = (nu + 63) >> 6;
        for (int strip = 0; strip < SB; ++strip) {
            const int j = strip*64 + lane;          // local pooled-u row
            float xin[9][4];
            #pragma unroll
            for (int f = 0; f < 9; ++f)
                #pragma unroll
                for (int d = 0; d < 4; ++d)
                    xin[f][d] = sm[SM_X + f*LXP + 2*j + d];   // max 513 < 514
            const int u = 4*r0 - 6 + j;
            const bool uok = (j < nu) && (u >= 0) && (u < 2049);
            for (int c = wid; c < 16; c += 4) {
                const int cu = __builtin_amdgcn_readfirstlane(c);
                const float* wp = w1 + cu*27;       // uniform -> s_load
                const float bc = b1[cu];
                float a0 = bc, a1 = bc;
                #pragma unroll
                for (int f = 0; f < 9; ++f)
                    #pragma unroll
                    for (int k = 0; k < 3; ++k) {
                        float wv = wp[f*3 + k];
                        a0 = fmaf(xin[f][k],   wv, a0);
                        a1 = fmaf(xin[f][k+1], wv, a1);
                    }
                float res = uok ? fmaxf(fmaxf(a0, a1), 0.f) : 0.f;
                if (j < nu) sm[SM_P1 + cu*LUP + j] = res;   // 0 = conv pad for stage C
            }
        }
    }
    __syncthreads();

    // ---- stage C: conv2(16->32,k3,p2)+relu+pool2 -> p2[o][m] (overwrites X) ----
    {
        const int SC = (nw + 63) >> 6;
        for (int strip = 0; strip < SC; ++strip) {
            const int m = strip*64 + lane;          // local pooled-w row
            float xin[16][4];
            #pragma unroll
            for (int ci = 0; ci < 16; ++ci)
                #pragma unroll
                for (int d = 0; d < 4; ++d)
                    xin[ci][d] = sm[SM_P1 + ci*LUP + 2*m + d];  // max 257 < 258
            const int w = 2*r0 - 2 + m;
            const bool wok = (m < nw) && (w >= 0) && (w < 1025);
            for (int o = wid; o < 32; o += 4) {
                const int ou = __builtin_amdgcn_readfirstlane(o);
                const float* wp = w2 + ou*48;
                const float bo = b2[ou];
                float a0 = bo, a1 = bo, a2 = 0.f, a3 = 0.f;
                #pragma unroll
                for (int ci = 0; ci < 16; ++ci)
                    #pragma unroll
                    for (int k = 0; k < 3; ++k) {
                        float wv = wp[ci*3 + k];
                        if (ci & 1) { a2 = fmaf(xin[ci][k], wv, a2); a3 = fmaf(xin[ci][k+1], wv, a3); }
                        else        { a0 = fmaf(xin[ci][k], wv, a0); a1 = fmaf(xin[ci][k+1], wv, a1); }
                    }
                a0 += a2; a1 += a3;
                float res = wok ? fmaxf(fmaxf(a0, a1), 0.f) : 0.f;
                if (m < nw) sm[SM_P2 + ou*LWP + m] = res;   // 0 = conv pad for stage D
            }
        }
    }
    __syncthreads();

    // ---- stage D: conv3(32->16,k3,p2)+relu+pool2 -> sum over r -> feat ----
    {
        const bool rok = (lane < nr);
        float acc[4][2];
        #pragma unroll
        for (int i = 0; i < 4; ++i) { acc[i][0] = 0.f; acc[i][1] = 0.f; }
        for (int h = 0; h < 2; ++h) {               // input-channel halves
            float xin[16][4];
            #pragma unroll
            for (int ci = 0; ci < 16; ++ci)
                #pragma unroll
                for (int d = 0; d < 4; ++d)
                    xin[ci][d] = sm[SM_P2 + (h*16 + ci)*LWP + 2*lane + d];  // max 129 < 130
            #pragma unroll
            for (int i = 0; i < 4; ++i) {
                const int ou = __builtin_amdgcn_readfirstlane(wid + 4*i);
                const float* wp = w3 + ou*96 + h*48;
                #pragma unroll
                for (int ci = 0; ci < 16; ++ci)
                    #pragma unroll
                    for (int k = 0; k < 3; ++k) {
                        float wv = wp[ci*3 + k];
                        acc[i][0] = fmaf(xin[ci][k],   wv, acc[i][0]);
                        acc[i][1] = fmaf(xin[ci][k+1], wv, acc[i][1]);
                    }
            }
        }
        #pragma unroll
        for (int i = 0; i < 4; ++i) {
            const int ou = __builtin_amdgcn_readfirstlane(wid + 4*i);
            const float bo = b3[ou];
            float v = fmaxf(fmaxf(acc[i][0] + bo, acc[i][1] + bo), 0.f);
            v = rok ? v : 0.f;
            #pragma unroll
            for (int off = 32; off >= 1; off >>= 1)
                v += __shfl_down(v, off, 64);
            if (lane == 0) atomicAdd(&feat[n*16 + ou], v);
        }
    }
}

// feat [2048,16] viewed as [256,128]; out[b][q] = max(feat[b,3q..3q+2]) / 513
__global__ void finalize_kernel(const float* __restrict__ feat, float* __restrict__ out) {
    int i = blockIdx.x * blockDim.x + threadIdx.x;
    if (i < 256*42) {
        int b = i / 42;
        int q = i - b*42;
        const float* f = feat + b*128 + q*3;
        out[i] = fmaxf(fmaxf(f[0], f[1]), f[2]) * (1.0f/513.0f);
    }
}

extern "C" void kernel_launch(void* const* d_in, const int* in_sizes, int n_in,
                              void* d_out, int out_size, void* d_ws, size_t ws_size,
                              hipStream_t stream) {
    const float* x  = (const float*)d_in[0];
    const float* w1 = (const float*)d_in[1];
    const float* b1 = (const float*)d_in[2];
    const float* w2 = (const float*)d_in[3];
    const float* b2 = (const float*)d_in[4];
    const float* w3 = (const float*)d_in[5];
    const float* b3 = (const float*)d_in[6];
    float* feat = (float*)d_ws;                       // 2048*16 floats = 128 KB
    hipMemsetAsync(feat, 0, NS*16*sizeof(float), stream);
    dim3 grid(NCHUNK, NS);
    fused_cnn<<<grid, 256, 0, stream>>>(x, w1, b1, w2, b2, w3, b3, feat);
    finalize_kernel<<<(256*42 + 255)/256, 256, 0, stream>>>(feat, (float*)d_out);
}